// Round 1
// baseline (12794.093 us; speedup 1.0000x reference)
//
#include <hip/hip_runtime.h>
#include <math.h>

#define TT   512
#define BB   64
#define EMBD 300
#define NU   512
#define G3   1536   // 3*UNITS

static constexpr size_t XW_FLOATS = (size_t)2 * TT * BB * G3;   // 100,663,296
static constexpr size_t UT_FLOATS = (size_t)2 * G3 * NU;        //   1,572,864
static constexpr size_t HB_FLOATS = (size_t)2 * 2 * BB * NU;    //     131,072

// ---------------- U transpose: Ut[dir][c][k] = U[dir][k][c] ----------------
__global__ __launch_bounds__(256) void k_transpose(const float* __restrict__ Uf,
                                                   const float* __restrict__ Ub,
                                                   float* __restrict__ Ut) {
  __shared__ float tile[32][33];
  const float* U = blockIdx.z ? Ub : Uf;
  float* out = Ut + (size_t)blockIdx.z * G3 * NU;
  int c0 = blockIdx.x * 32, k0 = blockIdx.y * 32;
  int j = threadIdx.x & 31, i0 = threadIdx.x >> 5;
  for (int i = i0; i < 32; i += 8)
    tile[i][j] = U[(size_t)(k0 + i) * G3 + c0 + j];
  __syncthreads();
  for (int i = i0; i < 32; i += 8)
    out[(size_t)(c0 + i) * NU + k0 + j] = tile[j][i];
}

// ------------- embedding gather + input GEMM: xw[dir][t][b][c] -------------
// grid: x = n-tile (24), y = t (512), z = dir (2). 64 rows (= batch) x 64 cols.
__global__ __launch_bounds__(256) void k_input_gemm(
    const int* __restrict__ tokens, const float* __restrict__ emb,
    const float* __restrict__ Wf, const float* __restrict__ bf,
    const float* __restrict__ Wb, const float* __restrict__ bb,
    float* __restrict__ xw) {
  __shared__ float As[8][72];   // [k][b], pad 72 -> 2-way max on staging writes
  __shared__ float Bs[8][64];   // [k][n]
  __shared__ int tok[64];
  const int t = blockIdx.y;
  const int n0 = blockIdx.x * 64;
  const int dir = blockIdx.z;
  const float* W = dir ? Wb : Wf;
  const float* bias = dir ? bb : bf;           // row 0 = input bias
  float* out = xw + (size_t)dir * TT * BB * G3;
  const int tid = threadIdx.x;
  if (tid < 64) tok[tid] = tokens[(size_t)tid * TT + t];
  __syncthreads();
  const int tx = tid & 15, ty = tid >> 4;
  float4 c0 = {0,0,0,0}, c1 = {0,0,0,0}, c2 = {0,0,0,0}, c3 = {0,0,0,0};
  for (int kc = 0; kc < 38; ++kc) {
    const int k0 = kc * 8;
    if (tid < 128) {           // stage B tile: one float4 each
      int kb = tid >> 4, nq = (tid & 15) * 4;
      float4 v = {0,0,0,0};
      if (k0 + kb < EMBD) v = *(const float4*)(W + (size_t)(k0 + kb) * G3 + n0 + nq);
      *(float4*)&Bs[kb][nq] = v;
    } else {                   // stage A tile: one float4 (4 k's of one token row)
      int th = tid - 128;
      int b = th >> 1, kh = (th & 1) * 4;
      float4 v = {0,0,0,0};
      if (k0 + kh + 4 <= EMBD) v = *(const float4*)(emb + (size_t)tok[b] * EMBD + k0 + kh);
      As[kh + 0][b] = v.x; As[kh + 1][b] = v.y; As[kh + 2][b] = v.z; As[kh + 3][b] = v.w;
    }
    __syncthreads();
    #pragma unroll
    for (int kb = 0; kb < 8; ++kb) {
      float4 bv = *(const float4*)&Bs[kb][tx * 4];
      float4 av = *(const float4*)&As[kb][ty * 4];
      c0.x = fmaf(av.x, bv.x, c0.x); c0.y = fmaf(av.x, bv.y, c0.y);
      c0.z = fmaf(av.x, bv.z, c0.z); c0.w = fmaf(av.x, bv.w, c0.w);
      c1.x = fmaf(av.y, bv.x, c1.x); c1.y = fmaf(av.y, bv.y, c1.y);
      c1.z = fmaf(av.y, bv.z, c1.z); c1.w = fmaf(av.y, bv.w, c1.w);
      c2.x = fmaf(av.z, bv.x, c2.x); c2.y = fmaf(av.z, bv.y, c2.y);
      c2.z = fmaf(av.z, bv.z, c2.z); c2.w = fmaf(av.z, bv.w, c2.w);
      c3.x = fmaf(av.w, bv.x, c3.x); c3.y = fmaf(av.w, bv.y, c3.y);
      c3.z = fmaf(av.w, bv.z, c3.z); c3.w = fmaf(av.w, bv.w, c3.w);
    }
    __syncthreads();
  }
  float4 bi = *(const float4*)(bias + n0 + tx * 4);
  size_t base = ((size_t)t * BB + (size_t)ty * 4) * G3 + n0 + tx * 4;
  float4 o;
  o.x = c0.x + bi.x; o.y = c0.y + bi.y; o.z = c0.z + bi.z; o.w = c0.w + bi.w;
  *(float4*)(out + base) = o;
  o.x = c1.x + bi.x; o.y = c1.y + bi.y; o.z = c1.z + bi.z; o.w = c1.w + bi.w;
  *(float4*)(out + base + G3) = o;
  o.x = c2.x + bi.x; o.y = c2.y + bi.y; o.z = c2.z + bi.z; o.w = c2.w + bi.w;
  *(float4*)(out + base + 2 * G3) = o;
  o.x = c3.x + bi.x; o.y = c3.y + bi.y; o.z = c3.z + bi.z; o.w = c3.w + bi.w;
  *(float4*)(out + base + 3 * G3) = o;
}

// --------------------------- persistent GRU scan ---------------------------
// 256 blocks: dir(2) x ublk(16, 32 units) x bblk(8, 8 batches). One block/CU.
// Group = (dir, bblk): 16 blocks exchange h via LLC-coherent atomics + a
// monotonic group barrier counter. No acquire fences (would invalidate L2).
__global__ __launch_bounds__(256) void k_gru(
    const float* __restrict__ xw, const float* __restrict__ Ut,
    const float* __restrict__ bf, const float* __restrict__ bb,
    float* __restrict__ hbuf, int* __restrict__ ctr,
    float* __restrict__ out, float* __restrict__ state) {
  __shared__ float hS[8][NU];          // h for this block's 8 batches, all units
  __shared__ float red[3][8][8][32];   // [gate][batch][ksplit][unit]
  const int wg = blockIdx.x;
  const int dir = wg >> 7;
  const int ublk = (wg >> 3) & 15;
  const int bblk = wg & 7;
  const int u0 = ublk * 32, b0 = bblk * 8;
  const int grp = dir * 8 + bblk;
  const int tid = threadIdx.x;
  const int ul = tid & 31;
  const int hi = tid >> 5;             // ksplit in compute phase, batch in reduce
  const float* xwd = xw + (size_t)dir * TT * BB * G3;
  const float* Uz = Ut + (size_t)dir * G3 * NU + (size_t)(u0 + ul) * NU;
  const float* Ur = Uz + (size_t)512 * NU;
  const float* Uh = Uz + (size_t)1024 * NU;
  const float* br = (dir ? bb : bf) + G3;   // row 1 = recurrent bias
  const float brz = br[u0 + ul], brr = br[512 + u0 + ul], brh = br[1024 + u0 + ul];
  float* hb = hbuf + (size_t)dir * 2 * BB * NU;

  #pragma unroll
  for (int j = 0; j < 16; ++j) hS[hi][ul + j * 32] = 0.f;   // h0 = 0
  __syncthreads();

  for (int s = 0; s < TT; ++s) {
    const int t = dir ? (TT - 1 - s) : s;
    float az[8], ar[8], ah[8];
    #pragma unroll
    for (int b = 0; b < 8; ++b) { az[b] = 0.f; ar[b] = 0.f; ah[b] = 0.f; }
    const int kb0 = hi * 64;
    #pragma unroll 2
    for (int k = kb0; k < kb0 + 64; k += 4) {
      float4 uz = *(const float4*)(Uz + k);
      float4 ur = *(const float4*)(Ur + k);
      float4 uh = *(const float4*)(Uh + k);
      #pragma unroll
      for (int b = 0; b < 8; ++b) {
        float4 hv = *(const float4*)&hS[b][k];
        az[b] = fmaf(uz.x, hv.x, az[b]); az[b] = fmaf(uz.y, hv.y, az[b]);
        az[b] = fmaf(uz.z, hv.z, az[b]); az[b] = fmaf(uz.w, hv.w, az[b]);
        ar[b] = fmaf(ur.x, hv.x, ar[b]); ar[b] = fmaf(ur.y, hv.y, ar[b]);
        ar[b] = fmaf(ur.z, hv.z, ar[b]); ar[b] = fmaf(ur.w, hv.w, ar[b]);
        ah[b] = fmaf(uh.x, hv.x, ah[b]); ah[b] = fmaf(uh.y, hv.y, ah[b]);
        ah[b] = fmaf(uh.z, hv.z, ah[b]); ah[b] = fmaf(uh.w, hv.w, ah[b]);
      }
    }
    #pragma unroll
    for (int b = 0; b < 8; ++b) {
      red[0][b][hi][ul] = az[b];
      red[1][b][hi][ul] = ar[b];
      red[2][b][hi][ul] = ah[b];
    }
    __syncthreads();
    float rz = 0.f, rr = 0.f, rh = 0.f;
    #pragma unroll
    for (int q = 0; q < 8; ++q) {
      rz += red[0][hi][q][ul];
      rr += red[1][hi][q][ul];
      rh += red[2][hi][q][ul];
    }
    const int bg = b0 + hi;
    const float* xp = xwd + ((size_t)t * BB + bg) * G3 + u0 + ul;
    const float xz = xp[0], xr = xp[512], xh = xp[1024];
    const float z = 1.f / (1.f + __expf(-(xz + rz + brz)));
    const float r = 1.f / (1.f + __expf(-(xr + rr + brr)));
    const float hh = tanhf(xh + r * (rh + brh));
    const float hold = hS[hi][u0 + ul];
    const float hn = z * hold + (1.f - z) * hh;
    // h exchange: agent-scope (LLC-coherent) store, bypasses per-XCD L2
    __hip_atomic_store(hb + ((size_t)(s & 1) * BB + bg) * NU + u0 + ul, hn,
                       __ATOMIC_RELAXED, __HIP_MEMORY_SCOPE_AGENT);
    out[((size_t)bg * TT + t) * 1024 + (size_t)dir * NU + u0 + ul] = hn;
    if (s == TT - 1) {
      state[(size_t)bg * 1024 + (size_t)dir * NU + u0 + ul] = hn;
    } else {
      __syncthreads();   // all lanes' h stores issued
      if (tid == 0) {
        // RELEASE: drains vmcnt + wbl2 (no L2 invalidate) before the add
        __hip_atomic_fetch_add(&ctr[grp], 1, __ATOMIC_RELEASE, __HIP_MEMORY_SCOPE_AGENT);
        const int target = 16 * (s + 1);
        while (__hip_atomic_load(&ctr[grp], __ATOMIC_RELAXED, __HIP_MEMORY_SCOPE_AGENT) < target) {
          __builtin_amdgcn_s_sleep(2);
        }
      }
      __syncthreads();
      // reload full h rows (agent-scope loads: read LLC, skip stale L2)
      const float* hr = hb + ((size_t)(s & 1) * BB + b0 + hi) * NU;
      #pragma unroll
      for (int j = 0; j < 16; ++j) {
        hS[hi][ul + j * 32] =
            __hip_atomic_load((float*)(hr + ul + j * 32), __ATOMIC_RELAXED,
                              __HIP_MEMORY_SCOPE_AGENT);
      }
      __syncthreads();
    }
  }
}

extern "C" void kernel_launch(void* const* d_in, const int* in_sizes, int n_in,
                              void* d_out, int out_size, void* d_ws, size_t ws_size,
                              hipStream_t stream) {
  (void)in_sizes; (void)n_in; (void)out_size; (void)ws_size;
  const int*   tokens = (const int*)d_in[0];
  const float* emb    = (const float*)d_in[1];
  const float* Wf     = (const float*)d_in[2];
  const float* Uf     = (const float*)d_in[3];
  const float* bf     = (const float*)d_in[4];
  const float* Wb     = (const float*)d_in[5];
  const float* Ub     = (const float*)d_in[6];
  const float* bb     = (const float*)d_in[7];
  float* ws = (float*)d_ws;
  float* xw = ws;
  float* Ut = ws + XW_FLOATS;
  float* hb = Ut + UT_FLOATS;
  int*   ctr = (int*)(hb + HB_FLOATS);
  float* out = (float*)d_out;
  float* state = out + (size_t)BB * TT * 1024;

  hipMemsetAsync(ctr, 0, 64, stream);
  hipLaunchKernelGGL(k_transpose, dim3(48, 16, 2), dim3(256), 0, stream, Uf, Ub, Ut);
  hipLaunchKernelGGL(k_input_gemm, dim3(24, 512, 2), dim3(256), 0, stream,
                     tokens, emb, Wf, bf, Wb, bb, xw);
  hipLaunchKernelGGL(k_gru, dim3(256), dim3(256), 0, stream,
                     xw, Ut, bf, bb, hb, ctr, out, state);
}

// Round 2
// 12682.095 us; speedup vs baseline: 1.0088x; 1.0088x over previous
//
#include <hip/hip_runtime.h>
#include <math.h>

#define TT   512
#define BB   64
#define EMBD 300
#define NU   512
#define G3   1536   // 3*UNITS

static constexpr size_t XW_FLOATS = (size_t)2 * TT * BB * G3;   // 100,663,296
static constexpr size_t HB_FLOATS = (size_t)2 * 2 * BB * NU;    //     131,072

// ------------- embedding gather + input GEMM: xw[dir][t][b][c] -------------
// grid: x = n-tile (24), y = t (512), z = dir (2). 64 rows (= batch) x 64 cols.
__global__ __launch_bounds__(256) void k_input_gemm(
    const int* __restrict__ tokens, const float* __restrict__ emb,
    const float* __restrict__ Wf, const float* __restrict__ bf,
    const float* __restrict__ Wb, const float* __restrict__ bb,
    float* __restrict__ xw) {
  __shared__ float As[8][72];   // [k][b]
  __shared__ float Bs[8][64];   // [k][n]
  __shared__ int tok[64];
  const int t = blockIdx.y;
  const int n0 = blockIdx.x * 64;
  const int dir = blockIdx.z;
  const float* W = dir ? Wb : Wf;
  const float* bias = dir ? bb : bf;           // row 0 = input bias
  float* out = xw + (size_t)dir * TT * BB * G3;
  const int tid = threadIdx.x;
  if (tid < 64) tok[tid] = tokens[(size_t)tid * TT + t];
  __syncthreads();
  const int tx = tid & 15, ty = tid >> 4;
  float4 c0 = {0,0,0,0}, c1 = {0,0,0,0}, c2 = {0,0,0,0}, c3 = {0,0,0,0};
  for (int kc = 0; kc < 38; ++kc) {
    const int k0 = kc * 8;
    if (tid < 128) {           // stage B tile: one float4 each
      int kb = tid >> 4, nq = (tid & 15) * 4;
      float4 v = {0,0,0,0};
      if (k0 + kb < EMBD) v = *(const float4*)(W + (size_t)(k0 + kb) * G3 + n0 + nq);
      *(float4*)&Bs[kb][nq] = v;
    } else {                   // stage A tile: one float4 (4 k's of one token row)
      int th = tid - 128;
      int b = th >> 1, kh = (th & 1) * 4;
      float4 v = {0,0,0,0};
      if (k0 + kh + 4 <= EMBD) v = *(const float4*)(emb + (size_t)tok[b] * EMBD + k0 + kh);
      As[kh + 0][b] = v.x; As[kh + 1][b] = v.y; As[kh + 2][b] = v.z; As[kh + 3][b] = v.w;
    }
    __syncthreads();
    #pragma unroll
    for (int kb = 0; kb < 8; ++kb) {
      float4 bv = *(const float4*)&Bs[kb][tx * 4];
      float4 av = *(const float4*)&As[kb][ty * 4];
      c0.x = fmaf(av.x, bv.x, c0.x); c0.y = fmaf(av.x, bv.y, c0.y);
      c0.z = fmaf(av.x, bv.z, c0.z); c0.w = fmaf(av.x, bv.w, c0.w);
      c1.x = fmaf(av.y, bv.x, c1.x); c1.y = fmaf(av.y, bv.y, c1.y);
      c1.z = fmaf(av.y, bv.z, c1.z); c1.w = fmaf(av.y, bv.w, c1.w);
      c2.x = fmaf(av.z, bv.x, c2.x); c2.y = fmaf(av.z, bv.y, c2.y);
      c2.z = fmaf(av.z, bv.z, c2.z); c2.w = fmaf(av.z, bv.w, c2.w);
      c3.x = fmaf(av.w, bv.x, c3.x); c3.y = fmaf(av.w, bv.y, c3.y);
      c3.z = fmaf(av.w, bv.z, c3.z); c3.w = fmaf(av.w, bv.w, c3.w);
    }
    __syncthreads();
  }
  float4 bi = *(const float4*)(bias + n0 + tx * 4);
  size_t base = ((size_t)t * BB + (size_t)ty * 4) * G3 + n0 + tx * 4;
  float4 o;
  o.x = c0.x + bi.x; o.y = c0.y + bi.y; o.z = c0.z + bi.z; o.w = c0.w + bi.w;
  *(float4*)(out + base) = o;
  o.x = c1.x + bi.x; o.y = c1.y + bi.y; o.z = c1.z + bi.z; o.w = c1.w + bi.w;
  *(float4*)(out + base + G3) = o;
  o.x = c2.x + bi.x; o.y = c2.y + bi.y; o.z = c2.z + bi.z; o.w = c2.w + bi.w;
  *(float4*)(out + base + 2 * G3) = o;
  o.x = c3.x + bi.x; o.y = c3.y + bi.y; o.z = c3.z + bi.z; o.w = c3.w + bi.w;
  *(float4*)(out + base + 3 * G3) = o;
}

// --------------------------- persistent GRU scan ---------------------------
// 256 blocks: dir(2) x ublk(16, 32 units) x bblk(8, 8 batches). One block/CU.
// U is REGISTER-RESIDENT: each thread holds its (1 unit x 3 gates x 64 k)
// slice = 192 VGPRs, loaded once. Zero U traffic in the 512-step loop.
// Group = (dir, bblk): 16 blocks exchange h via LLC-coherent atomics + a
// monotonic group barrier counter. No acquire fences (would invalidate L2).
__global__ __launch_bounds__(256, 1) void k_gru(
    const float* __restrict__ xw,
    const float* __restrict__ Uf, const float* __restrict__ Ub,
    const float* __restrict__ bf, const float* __restrict__ bb,
    float* __restrict__ hbuf, int* __restrict__ ctr,
    float* __restrict__ out, float* __restrict__ state) {
  __shared__ float hS[8][NU];          // h for this block's 8 batches, all units
  __shared__ float red[3][8][8][32];   // [gate][batch][ksplit][unit]
  const int wg = blockIdx.x;
  const int dir = wg >> 7;
  const int ublk = (wg >> 3) & 15;
  const int bblk = wg & 7;
  const int u0 = ublk * 32, b0 = bblk * 8;
  const int grp = dir * 8 + bblk;
  const int tid = threadIdx.x;
  const int ul = tid & 31;
  const int hi = tid >> 5;             // ksplit in compute phase, batch in reduce
  const int kb0 = hi * 64;
  const float* xwd = xw + (size_t)dir * TT * BB * G3;
  const float* U = dir ? Ub : Uf;      // [k][c] layout, c = gate*512 + unit
  const float* br = (dir ? bb : bf) + G3;   // row 1 = recurrent bias
  const float brz = br[u0 + ul], brr = br[512 + u0 + ul], brh = br[1024 + u0 + ul];
  float* hb = hbuf + (size_t)dir * 2 * BB * NU;

  // ---- preload this thread's U slice into registers (192 VGPRs) ----
  float Uz_r[64], Ur_r[64], Uh_r[64];
  #pragma unroll
  for (int kk = 0; kk < 64; ++kk) {
    const float* row = U + (size_t)(kb0 + kk) * G3 + u0 + ul;
    Uz_r[kk] = row[0];
    Ur_r[kk] = row[512];
    Uh_r[kk] = row[1024];
  }

  #pragma unroll
  for (int j = 0; j < 16; ++j) hS[hi][ul + j * 32] = 0.f;   // h0 = 0
  __syncthreads();

  for (int s = 0; s < TT; ++s) {
    const int t = dir ? (TT - 1 - s) : s;
    float az[8], ar[8], ah[8];
    #pragma unroll
    for (int b = 0; b < 8; ++b) { az[b] = 0.f; ar[b] = 0.f; ah[b] = 0.f; }
    #pragma unroll
    for (int q = 0; q < 16; ++q) {
      #pragma unroll
      for (int b = 0; b < 8; ++b) {
        float4 hv = *(const float4*)&hS[b][kb0 + q * 4];
        az[b] = fmaf(Uz_r[q*4+0], hv.x, az[b]); az[b] = fmaf(Uz_r[q*4+1], hv.y, az[b]);
        az[b] = fmaf(Uz_r[q*4+2], hv.z, az[b]); az[b] = fmaf(Uz_r[q*4+3], hv.w, az[b]);
        ar[b] = fmaf(Ur_r[q*4+0], hv.x, ar[b]); ar[b] = fmaf(Ur_r[q*4+1], hv.y, ar[b]);
        ar[b] = fmaf(Ur_r[q*4+2], hv.z, ar[b]); ar[b] = fmaf(Ur_r[q*4+3], hv.w, ar[b]);
        ah[b] = fmaf(Uh_r[q*4+0], hv.x, ah[b]); ah[b] = fmaf(Uh_r[q*4+1], hv.y, ah[b]);
        ah[b] = fmaf(Uh_r[q*4+2], hv.z, ah[b]); ah[b] = fmaf(Uh_r[q*4+3], hv.w, ah[b]);
      }
    }
    #pragma unroll
    for (int b = 0; b < 8; ++b) {
      red[0][b][hi][ul] = az[b];
      red[1][b][hi][ul] = ar[b];
      red[2][b][hi][ul] = ah[b];
    }
    __syncthreads();
    float rz = 0.f, rr = 0.f, rh = 0.f;
    #pragma unroll
    for (int q = 0; q < 8; ++q) {
      rz += red[0][hi][q][ul];
      rr += red[1][hi][q][ul];
      rh += red[2][hi][q][ul];
    }
    const int bg = b0 + hi;
    const float* xp = xwd + ((size_t)t * BB + bg) * G3 + u0 + ul;
    const float xz = xp[0], xr = xp[512], xh = xp[1024];
    const float z = 1.f / (1.f + __expf(-(xz + rz + brz)));
    const float r = 1.f / (1.f + __expf(-(xr + rr + brr)));
    const float hh = tanhf(xh + r * (rh + brh));
    const float hold = hS[hi][u0 + ul];
    const float hn = z * hold + (1.f - z) * hh;
    // h exchange: agent-scope (LLC-coherent) store, bypasses per-XCD L2
    __hip_atomic_store(hb + ((size_t)(s & 1) * BB + bg) * NU + u0 + ul, hn,
                       __ATOMIC_RELAXED, __HIP_MEMORY_SCOPE_AGENT);
    out[((size_t)bg * TT + t) * 1024 + (size_t)dir * NU + u0 + ul] = hn;
    if (s == TT - 1) {
      state[(size_t)bg * 1024 + (size_t)dir * NU + u0 + ul] = hn;
    } else {
      __syncthreads();   // all lanes' h stores issued + drained (vmcnt in barrier)
      if (tid == 0) {
        // RELEASE: drains vmcnt + wbl2 (no L2 invalidate) before the add
        __hip_atomic_fetch_add(&ctr[grp], 1, __ATOMIC_RELEASE, __HIP_MEMORY_SCOPE_AGENT);
        const int target = 16 * (s + 1);
        while (__hip_atomic_load(&ctr[grp], __ATOMIC_RELAXED, __HIP_MEMORY_SCOPE_AGENT) < target) {
          __builtin_amdgcn_s_sleep(2);
        }
      }
      __syncthreads();
      // reload full h rows (agent-scope loads: read LLC, skip stale L2)
      const float* hr = hb + ((size_t)(s & 1) * BB + b0 + hi) * NU;
      #pragma unroll
      for (int j = 0; j < 16; ++j) {
        hS[hi][ul + j * 32] =
            __hip_atomic_load((float*)(hr + ul + j * 32), __ATOMIC_RELAXED,
                              __HIP_MEMORY_SCOPE_AGENT);
      }
      __syncthreads();
    }
  }
}

extern "C" void kernel_launch(void* const* d_in, const int* in_sizes, int n_in,
                              void* d_out, int out_size, void* d_ws, size_t ws_size,
                              hipStream_t stream) {
  (void)in_sizes; (void)n_in; (void)out_size; (void)ws_size;
  const int*   tokens = (const int*)d_in[0];
  const float* emb    = (const float*)d_in[1];
  const float* Wf     = (const float*)d_in[2];
  const float* Uf     = (const float*)d_in[3];
  const float* bf     = (const float*)d_in[4];
  const float* Wb     = (const float*)d_in[5];
  const float* Ub     = (const float*)d_in[6];
  const float* bb     = (const float*)d_in[7];
  float* ws = (float*)d_ws;
  float* xw = ws;
  float* hb = ws + XW_FLOATS;
  int*   ctr = (int*)(hb + HB_FLOATS);
  float* out = (float*)d_out;
  float* state = out + (size_t)BB * TT * 1024;

  hipMemsetAsync(ctr, 0, 64, stream);
  hipLaunchKernelGGL(k_input_gemm, dim3(24, 512, 2), dim3(256), 0, stream,
                     tokens, emb, Wf, bf, Wb, bb, xw);
  hipLaunchKernelGGL(k_gru, dim3(256), dim3(256), 0, stream,
                     xw, Uf, Ub, bf, bb, hb, ctr, out, state);
}

// Round 3
// 10021.455 us; speedup vs baseline: 1.2767x; 1.2655x over previous
//
#include <hip/hip_runtime.h>
#include <math.h>

#define TT   512
#define BB   64
#define EMBD 300
#define NU   512
#define G3   1536   // 3*UNITS

static constexpr size_t XW_FLOATS = (size_t)2 * TT * BB * G3;   // 100,663,296
static constexpr size_t HB_FLOATS = (size_t)2 * 2 * BB * NU;    //     131,072
#define UROW 516    // padded K-stride for LDS rows (breaks pow-2 bank aliasing)

// ------------- embedding gather + input GEMM: xw[dir][t][b][c] -------------
__global__ __launch_bounds__(256) void k_input_gemm(
    const int* __restrict__ tokens, const float* __restrict__ emb,
    const float* __restrict__ Wf, const float* __restrict__ bf,
    const float* __restrict__ Wb, const float* __restrict__ bb,
    float* __restrict__ xw) {
  __shared__ float As[8][72];   // [k][b]
  __shared__ float Bs[8][64];   // [k][n]
  __shared__ int tok[64];
  const int t = blockIdx.y;
  const int n0 = blockIdx.x * 64;
  const int dir = blockIdx.z;
  const float* W = dir ? Wb : Wf;
  const float* bias = dir ? bb : bf;           // row 0 = input bias
  float* out = xw + (size_t)dir * TT * BB * G3;
  const int tid = threadIdx.x;
  if (tid < 64) tok[tid] = tokens[(size_t)tid * TT + t];
  __syncthreads();
  const int tx = tid & 15, ty = tid >> 4;
  float4 c0 = {0,0,0,0}, c1 = {0,0,0,0}, c2 = {0,0,0,0}, c3 = {0,0,0,0};
  for (int kc = 0; kc < 38; ++kc) {
    const int k0 = kc * 8;
    if (tid < 128) {
      int kb = tid >> 4, nq = (tid & 15) * 4;
      float4 v = {0,0,0,0};
      if (k0 + kb < EMBD) v = *(const float4*)(W + (size_t)(k0 + kb) * G3 + n0 + nq);
      *(float4*)&Bs[kb][nq] = v;
    } else {
      int th = tid - 128;
      int b = th >> 1, kh = (th & 1) * 4;
      float4 v = {0,0,0,0};
      if (k0 + kh + 4 <= EMBD) v = *(const float4*)(emb + (size_t)tok[b] * EMBD + k0 + kh);
      As[kh + 0][b] = v.x; As[kh + 1][b] = v.y; As[kh + 2][b] = v.z; As[kh + 3][b] = v.w;
    }
    __syncthreads();
    #pragma unroll
    for (int kb = 0; kb < 8; ++kb) {
      float4 bv = *(const float4*)&Bs[kb][tx * 4];
      float4 av = *(const float4*)&As[kb][ty * 4];
      c0.x = fmaf(av.x, bv.x, c0.x); c0.y = fmaf(av.x, bv.y, c0.y);
      c0.z = fmaf(av.x, bv.z, c0.z); c0.w = fmaf(av.x, bv.w, c0.w);
      c1.x = fmaf(av.y, bv.x, c1.x); c1.y = fmaf(av.y, bv.y, c1.y);
      c1.z = fmaf(av.y, bv.z, c1.z); c1.w = fmaf(av.y, bv.w, c1.w);
      c2.x = fmaf(av.z, bv.x, c2.x); c2.y = fmaf(av.z, bv.y, c2.y);
      c2.z = fmaf(av.z, bv.z, c2.z); c2.w = fmaf(av.z, bv.w, c2.w);
      c3.x = fmaf(av.w, bv.x, c3.x); c3.y = fmaf(av.w, bv.y, c3.y);
      c3.z = fmaf(av.w, bv.z, c3.z); c3.w = fmaf(av.w, bv.w, c3.w);
    }
    __syncthreads();
  }
  float4 bi = *(const float4*)(bias + n0 + tx * 4);
  size_t base = ((size_t)t * BB + (size_t)ty * 4) * G3 + n0 + tx * 4;
  float4 o;
  o.x = c0.x + bi.x; o.y = c0.y + bi.y; o.z = c0.z + bi.z; o.w = c0.w + bi.w;
  *(float4*)(out + base) = o;
  o.x = c1.x + bi.x; o.y = c1.y + bi.y; o.z = c1.z + bi.z; o.w = c1.w + bi.w;
  *(float4*)(out + base + G3) = o;
  o.x = c2.x + bi.x; o.y = c2.y + bi.y; o.z = c2.z + bi.z; o.w = c2.w + bi.w;
  *(float4*)(out + base + 2 * G3) = o;
  o.x = c3.x + bi.x; o.y = c3.y + bi.y; o.z = c3.z + bi.z; o.w = c3.w + bi.w;
  *(float4*)(out + base + 3 * G3) = o;
}

// --------------------------- persistent GRU scan ---------------------------
// 256 blocks = dir(2) x ublk(32, 16 units) x bblk(4, 16 batches). 1 block/CU
// (enforced by 132 KB LDS). U slice lives in LDS (98 KB) -- structural
// on-chip residency, no allocator dependence. Thread = (unit, batch), owns
// full K=512: no reduction phase, ~40 VGPRs.
// Group = (dir, bblk): 32 blocks exchange h via LLC-coherent atomics + a
// monotonic group barrier counter. No acquire fences (would invalidate L2).
__global__ __launch_bounds__(256) void k_gru(
    const float* __restrict__ xw,
    const float* __restrict__ Uf, const float* __restrict__ Ub,
    const float* __restrict__ bf, const float* __restrict__ bb,
    float* __restrict__ hbuf, int* __restrict__ ctr,
    float* __restrict__ out, float* __restrict__ state) {
  extern __shared__ float smem[];
  float* Ul = smem;                 // [48][UROW], row = u*3 + gate
  float* hS = smem + 48 * UROW;     // [16][UROW]
  const int wg = blockIdx.x;
  const int dir = wg >> 7;
  const int ublk = (wg >> 2) & 31;
  const int bblk = wg & 3;
  const int u0 = ublk * 16, b0 = bblk * 16;
  const int grp = dir * 4 + bblk;
  const int tid = threadIdx.x;
  const int u = tid & 15;           // local unit
  const int b = tid >> 4;           // local batch
  const float* U = dir ? Ub : Uf;   // [k][c], c = gate*512 + unit
  const float* br = (dir ? bb : bf) + G3;   // row 1 = recurrent bias
  const float brz = br[u0 + u], brr = br[512 + u0 + u], brh = br[1024 + u0 + u];
  const float* xwd = xw + (size_t)dir * TT * BB * G3;
  float* hb = hbuf + (size_t)dir * 2 * BB * NU;

  // ---- one-time: stage this block's U slice into LDS ----
  for (int i = tid; i < 48 * 512; i += 256) {
    int c = i % 48, k = i / 48;            // 48-col span: mostly coalesced
    int g = c >> 4, uu = c & 15;
    Ul[(uu * 3 + g) * UROW + k] = U[(size_t)k * G3 + g * 512 + u0 + uu];
  }
  for (int i = tid; i < 16 * UROW; i += 256) hS[i] = 0.f;   // h0 = 0 (+pads)
  __syncthreads();

  const float* Uzr = Ul + (u * 3 + 0) * UROW;
  const float* Urr = Ul + (u * 3 + 1) * UROW;
  const float* Uhr = Ul + (u * 3 + 2) * UROW;
  const float* hrow = hS + b * UROW;

  for (int s = 0; s < TT; ++s) {
    const int t = dir ? (TT - 1 - s) : s;
    // prefetch gate pre-activations (LLC latency hidden under compute)
    const float* xp = xwd + ((size_t)t * BB + b0 + b) * G3 + u0 + u;
    const float xz = xp[0], xr = xp[512], xh = xp[1024];
    // rec = U . h over full K=512; 6 interleaved chains cover FMA latency
    float az0 = 0.f, az1 = 0.f, ar0 = 0.f, ar1 = 0.f, ah0 = 0.f, ah1 = 0.f;
    #pragma unroll 16
    for (int q = 0; q < 128; ++q) {
      float4 hv = *(const float4*)(hrow + q * 4);
      float4 uz = *(const float4*)(Uzr + q * 4);
      float4 ur = *(const float4*)(Urr + q * 4);
      float4 uh = *(const float4*)(Uhr + q * 4);
      az0 = fmaf(uz.x, hv.x, az0); az1 = fmaf(uz.y, hv.y, az1);
      az0 = fmaf(uz.z, hv.z, az0); az1 = fmaf(uz.w, hv.w, az1);
      ar0 = fmaf(ur.x, hv.x, ar0); ar1 = fmaf(ur.y, hv.y, ar1);
      ar0 = fmaf(ur.z, hv.z, ar0); ar1 = fmaf(ur.w, hv.w, ar1);
      ah0 = fmaf(uh.x, hv.x, ah0); ah1 = fmaf(uh.y, hv.y, ah1);
      ah0 = fmaf(uh.z, hv.z, ah0); ah1 = fmaf(uh.w, hv.w, ah1);
    }
    const float rz = az0 + az1, rr = ar0 + ar1, rh = ah0 + ah1;
    const float z = 1.f / (1.f + __expf(-(xz + rz + brz)));
    const float r = 1.f / (1.f + __expf(-(xr + rr + brr)));
    const float hh = tanhf(xh + r * (rh + brh));
    const float hold = hrow[u0 + u];
    const float hn = z * hold + (1.f - z) * hh;
    // h exchange: agent-scope (LLC-coherent) store, bypasses per-XCD L2
    __hip_atomic_store(hb + ((size_t)(s & 1) * BB + b0 + b) * NU + u0 + u, hn,
                       __ATOMIC_RELAXED, __HIP_MEMORY_SCOPE_AGENT);
    out[((size_t)(b0 + b) * TT + t) * 1024 + (size_t)dir * NU + u0 + u] = hn;
    if (s == TT - 1) {
      state[(size_t)(b0 + b) * 1024 + (size_t)dir * NU + u0 + u] = hn;
    } else {
      __syncthreads();   // all lanes' h stores issued
      if (tid == 0) {
        // RELEASE: drains vmcnt + wbl2 (no L2 invalidate) before the add
        __hip_atomic_fetch_add(&ctr[grp], 1, __ATOMIC_RELEASE, __HIP_MEMORY_SCOPE_AGENT);
        const int target = 32 * (s + 1);
        while (__hip_atomic_load(&ctr[grp], __ATOMIC_RELAXED, __HIP_MEMORY_SCOPE_AGENT) < target) {
          __builtin_amdgcn_s_sleep(2);
        }
      }
      __syncthreads();
      // reload full h rows for our 16 batches (agent loads: LLC, skip stale L2)
      const float* hsrc = hb + (size_t)(s & 1) * BB * NU;
      for (int i = tid; i < 16 * 128; i += 256) {
        int bb2 = i >> 7, k4 = (i & 127) * 4;
        const float* p = hsrc + (size_t)(b0 + bb2) * NU + k4;
        float v0 = __hip_atomic_load((float*)(p + 0), __ATOMIC_RELAXED, __HIP_MEMORY_SCOPE_AGENT);
        float v1 = __hip_atomic_load((float*)(p + 1), __ATOMIC_RELAXED, __HIP_MEMORY_SCOPE_AGENT);
        float v2 = __hip_atomic_load((float*)(p + 2), __ATOMIC_RELAXED, __HIP_MEMORY_SCOPE_AGENT);
        float v3 = __hip_atomic_load((float*)(p + 3), __ATOMIC_RELAXED, __HIP_MEMORY_SCOPE_AGENT);
        float* d = hS + bb2 * UROW + k4;
        d[0] = v0; d[1] = v1; d[2] = v2; d[3] = v3;
      }
      __syncthreads();
    }
  }
}

extern "C" void kernel_launch(void* const* d_in, const int* in_sizes, int n_in,
                              void* d_out, int out_size, void* d_ws, size_t ws_size,
                              hipStream_t stream) {
  (void)in_sizes; (void)n_in; (void)out_size; (void)ws_size;
  const int*   tokens = (const int*)d_in[0];
  const float* emb    = (const float*)d_in[1];
  const float* Wf     = (const float*)d_in[2];
  const float* Uf     = (const float*)d_in[3];
  const float* bf     = (const float*)d_in[4];
  const float* Wb     = (const float*)d_in[5];
  const float* Ub     = (const float*)d_in[6];
  const float* bb     = (const float*)d_in[7];
  float* ws = (float*)d_ws;
  float* xw = ws;
  float* hb = ws + XW_FLOATS;
  int*   ctr = (int*)(hb + HB_FLOATS);
  float* out = (float*)d_out;
  float* state = out + (size_t)BB * TT * 1024;

  hipMemsetAsync(ctr, 0, 64, stream);
  hipLaunchKernelGGL(k_input_gemm, dim3(24, 512, 2), dim3(256), 0, stream,
                     tokens, emb, Wf, bf, Wb, bb, xw);
  const size_t lds_bytes = (size_t)(48 + 16) * UROW * sizeof(float);  // 132096
  hipLaunchKernelGGL(k_gru, dim3(256), dim3(256), lds_bytes, stream,
                     xw, Uf, Ub, bf, bb, hb, ctr, out, state);
}

// Round 4
// 6177.467 us; speedup vs baseline: 2.0711x; 1.6223x over previous
//
#include <hip/hip_runtime.h>
#include <math.h>

#define TT   512
#define BB   64
#define EMBD 300
#define NU   512
#define G3   1536   // 3*UNITS

static constexpr size_t XW_FLOATS = (size_t)2 * TT * BB * G3;   // 100,663,296
static constexpr size_t HB_FLOATS = (size_t)2 * 2 * BB * NU;    //     131,072

// ------------- embedding gather + input GEMM: xw[dir][t][b][c] -------------
__global__ __launch_bounds__(256) void k_input_gemm(
    const int* __restrict__ tokens, const float* __restrict__ emb,
    const float* __restrict__ Wf, const float* __restrict__ bf,
    const float* __restrict__ Wb, const float* __restrict__ bb,
    float* __restrict__ xw) {
  __shared__ float As[8][72];   // [k][b]
  __shared__ float Bs[8][64];   // [k][n]
  __shared__ int tok[64];
  const int t = blockIdx.y;
  const int n0 = blockIdx.x * 64;
  const int dir = blockIdx.z;
  const float* W = dir ? Wb : Wf;
  const float* bias = dir ? bb : bf;           // row 0 = input bias
  float* out = xw + (size_t)dir * TT * BB * G3;
  const int tid = threadIdx.x;
  if (tid < 64) tok[tid] = tokens[(size_t)tid * TT + t];
  __syncthreads();
  const int tx = tid & 15, ty = tid >> 4;
  float4 c0 = {0,0,0,0}, c1 = {0,0,0,0}, c2 = {0,0,0,0}, c3 = {0,0,0,0};
  for (int kc = 0; kc < 38; ++kc) {
    const int k0 = kc * 8;
    if (tid < 128) {
      int kb = tid >> 4, nq = (tid & 15) * 4;
      float4 v = {0,0,0,0};
      if (k0 + kb < EMBD) v = *(const float4*)(W + (size_t)(k0 + kb) * G3 + n0 + nq);
      *(float4*)&Bs[kb][nq] = v;
    } else {
      int th = tid - 128;
      int b = th >> 1, kh = (th & 1) * 4;
      float4 v = {0,0,0,0};
      if (k0 + kh + 4 <= EMBD) v = *(const float4*)(emb + (size_t)tok[b] * EMBD + k0 + kh);
      As[kh + 0][b] = v.x; As[kh + 1][b] = v.y; As[kh + 2][b] = v.z; As[kh + 3][b] = v.w;
    }
    __syncthreads();
    #pragma unroll
    for (int kb = 0; kb < 8; ++kb) {
      float4 bv = *(const float4*)&Bs[kb][tx * 4];
      float4 av = *(const float4*)&As[kb][ty * 4];
      c0.x = fmaf(av.x, bv.x, c0.x); c0.y = fmaf(av.x, bv.y, c0.y);
      c0.z = fmaf(av.x, bv.z, c0.z); c0.w = fmaf(av.x, bv.w, c0.w);
      c1.x = fmaf(av.y, bv.x, c1.x); c1.y = fmaf(av.y, bv.y, c1.y);
      c1.z = fmaf(av.y, bv.z, c1.z); c1.w = fmaf(av.y, bv.w, c1.w);
      c2.x = fmaf(av.z, bv.x, c2.x); c2.y = fmaf(av.z, bv.y, c2.y);
      c2.z = fmaf(av.z, bv.z, c2.z); c2.w = fmaf(av.z, bv.w, c2.w);
      c3.x = fmaf(av.w, bv.x, c3.x); c3.y = fmaf(av.w, bv.y, c3.y);
      c3.z = fmaf(av.w, bv.z, c3.z); c3.w = fmaf(av.w, bv.w, c3.w);
    }
    __syncthreads();
  }
  float4 bi = *(const float4*)(bias + n0 + tx * 4);
  size_t base = ((size_t)t * BB + (size_t)ty * 4) * G3 + n0 + tx * 4;
  float4 o;
  o.x = c0.x + bi.x; o.y = c0.y + bi.y; o.z = c0.z + bi.z; o.w = c0.w + bi.w;
  *(float4*)(out + base) = o;
  o.x = c1.x + bi.x; o.y = c1.y + bi.y; o.z = c1.z + bi.z; o.w = c1.w + bi.w;
  *(float4*)(out + base + G3) = o;
  o.x = c2.x + bi.x; o.y = c2.y + bi.y; o.z = c2.z + bi.z; o.w = c2.w + bi.w;
  *(float4*)(out + base + 2 * G3) = o;
  o.x = c3.x + bi.x; o.y = c3.y + bi.y; o.z = c3.z + bi.z; o.w = c3.w + bi.w;
  *(float4*)(out + base + 3 * G3) = o;
}

// --------------------------- persistent GRU scan ---------------------------
// 256 blocks = dir(2) x bblk(8, 8 batches) x ublk(16, 32 units). 1/CU.
// U is REGISTER-RESIDENT (192 VGPRs/thread), PINNED via empty asm so the
// allocator cannot sink the preload back into the loop (round-2 failure).
// Thread = (u, ksplit): 32u x 8 ksplits of 64k, accumulates 8 batches in
// registers; h reads from LDS are 2-address broadcast (cheap); ksplit
// reduction via LDS. Group = (dir,bblk): 16 blocks, padded counters.
__global__ __launch_bounds__(256, 1) void k_gru(
    const float* __restrict__ xw,
    const float* __restrict__ Uf, const float* __restrict__ Ub,
    const float* __restrict__ bf, const float* __restrict__ bb,
    float* __restrict__ hbuf, int* __restrict__ ctr,
    float* __restrict__ out, float* __restrict__ state) {
  __shared__ float hS[8][NU];          // h for this block's 8 batches
  __shared__ float red[3][8][8][32];   // [gate][batch][ksplit][unit]
  const int wg = blockIdx.x;
  const int dir = wg >> 7;
  const int bblk = (wg >> 4) & 7;
  const int ublk = wg & 15;
  const int u0 = ublk * 32, b0 = bblk * 8;
  int* gctr = ctr + (dir * 8 + bblk) * 32;   // 128B-spaced counters
  const int tid = threadIdx.x;
  const int u = tid & 31;              // local unit
  const int hi = tid >> 5;             // ksplit in compute, batch in epilogue
  const int kb0 = hi * 64;
  const float* xwd = xw + (size_t)dir * TT * BB * G3;
  const float* U = dir ? Ub : Uf;      // [k][c], c = gate*512 + unit
  const float* br = (dir ? bb : bf) + G3;   // row 1 = recurrent bias
  const float brz = br[u0 + u], brr = br[512 + u0 + u], brh = br[1024 + u0 + u];
  float* hb = hbuf + (size_t)dir * 2 * BB * NU;

  // ---- preload this thread's U slice into registers, then PIN ----
  float Uz_r[64], Ur_r[64], Uh_r[64];
  #pragma unroll
  for (int kk = 0; kk < 64; ++kk) {
    const float* row = U + (size_t)(kb0 + kk) * G3 + u0 + u;
    Uz_r[kk] = row[0];
    Ur_r[kk] = row[512];
    Uh_r[kk] = row[1024];
  }
  #pragma unroll
  for (int kk = 0; kk < 64; ++kk) {
    asm volatile("" : "+v"(Uz_r[kk]), "+v"(Ur_r[kk]), "+v"(Uh_r[kk]));
  }

  #pragma unroll
  for (int j = 0; j < 16; ++j) hS[hi][u + j * 32] = 0.f;   // h0 = 0
  __syncthreads();

  for (int s = 0; s < TT; ++s) {
    const int t = dir ? (TT - 1 - s) : s;
    // prefetch this thread's gate pre-activations (batch = hi)
    const float* xp = xwd + ((size_t)t * BB + b0 + hi) * G3 + u0 + u;
    const float xz = xp[0], xr = xp[512], xh = xp[1024];
    float az[8], ar[8], ah[8];
    #pragma unroll
    for (int b = 0; b < 8; ++b) { az[b] = 0.f; ar[b] = 0.f; ah[b] = 0.f; }
    #pragma unroll
    for (int q = 0; q < 16; ++q) {
      #pragma unroll
      for (int b = 0; b < 8; ++b) {
        float4 hv = *(const float4*)&hS[b][kb0 + q * 4];   // 2-addr broadcast
        az[b] = fmaf(Uz_r[q*4+0], hv.x, az[b]); az[b] = fmaf(Uz_r[q*4+1], hv.y, az[b]);
        az[b] = fmaf(Uz_r[q*4+2], hv.z, az[b]); az[b] = fmaf(Uz_r[q*4+3], hv.w, az[b]);
        ar[b] = fmaf(Ur_r[q*4+0], hv.x, ar[b]); ar[b] = fmaf(Ur_r[q*4+1], hv.y, ar[b]);
        ar[b] = fmaf(Ur_r[q*4+2], hv.z, ar[b]); ar[b] = fmaf(Ur_r[q*4+3], hv.w, ar[b]);
        ah[b] = fmaf(Uh_r[q*4+0], hv.x, ah[b]); ah[b] = fmaf(Uh_r[q*4+1], hv.y, ah[b]);
        ah[b] = fmaf(Uh_r[q*4+2], hv.z, ah[b]); ah[b] = fmaf(Uh_r[q*4+3], hv.w, ah[b]);
      }
    }
    #pragma unroll
    for (int b = 0; b < 8; ++b) {
      red[0][b][hi][u] = az[b];
      red[1][b][hi][u] = ar[b];
      red[2][b][hi][u] = ah[b];
    }
    __syncthreads();
    float rz = 0.f, rr = 0.f, rh = 0.f;
    #pragma unroll
    for (int q = 0; q < 8; ++q) {
      rz += red[0][hi][q][u];
      rr += red[1][hi][q][u];
      rh += red[2][hi][q][u];
    }
    const int bg = b0 + hi;
    const float z = 1.f / (1.f + __expf(-(xz + rz + brz)));
    const float r = 1.f / (1.f + __expf(-(xr + rr + brr)));
    const float hh = tanhf(xh + r * (rh + brh));
    const float hold = hS[hi][u0 + u];
    const float hn = z * hold + (1.f - z) * hh;
    // h exchange: agent-scope (LLC-coherent) store, bypasses per-XCD L2
    __hip_atomic_store(hb + ((size_t)(s & 1) * BB + bg) * NU + u0 + u, hn,
                       __ATOMIC_RELAXED, __HIP_MEMORY_SCOPE_AGENT);
    out[((size_t)bg * TT + t) * 1024 + (size_t)dir * NU + u0 + u] = hn;
    if (s == TT - 1) {
      state[(size_t)bg * 1024 + (size_t)dir * NU + u0 + u] = hn;
    } else {
      __syncthreads();   // all lanes' h stores drained (vmcnt in barrier)
      if (tid == 0) {
        // RELEASE: drains vmcnt + wbl2 (no L2 invalidate) before the add
        __hip_atomic_fetch_add(gctr, 1, __ATOMIC_RELEASE, __HIP_MEMORY_SCOPE_AGENT);
        const int target = 16 * (s + 1);
        while (__hip_atomic_load(gctr, __ATOMIC_RELAXED, __HIP_MEMORY_SCOPE_AGENT) < target) {
          __builtin_amdgcn_s_sleep(2);
        }
      }
      __syncthreads();
      // reload h for our 8 batches, all 512 units (16 KB): 4 float4/thread
      const float* hsrc = hb + (size_t)(s & 1) * BB * NU;
      #pragma unroll
      for (int j = 0; j < 4; ++j) {
        int fi = tid + j * 256;              // float4 index
        int bl = fi >> 7, k4 = (fi & 127) * 4;
        const float* p = hsrc + (size_t)(b0 + bl) * NU + k4;
        float v0 = __hip_atomic_load((float*)(p + 0), __ATOMIC_RELAXED, __HIP_MEMORY_SCOPE_AGENT);
        float v1 = __hip_atomic_load((float*)(p + 1), __ATOMIC_RELAXED, __HIP_MEMORY_SCOPE_AGENT);
        float v2 = __hip_atomic_load((float*)(p + 2), __ATOMIC_RELAXED, __HIP_MEMORY_SCOPE_AGENT);
        float v3 = __hip_atomic_load((float*)(p + 3), __ATOMIC_RELAXED, __HIP_MEMORY_SCOPE_AGENT);
        float* d = &hS[bl][k4];
        d[0] = v0; d[1] = v1; d[2] = v2; d[3] = v3;
      }
      __syncthreads();
    }
  }
}

extern "C" void kernel_launch(void* const* d_in, const int* in_sizes, int n_in,
                              void* d_out, int out_size, void* d_ws, size_t ws_size,
                              hipStream_t stream) {
  (void)in_sizes; (void)n_in; (void)out_size; (void)ws_size;
  const int*   tokens = (const int*)d_in[0];
  const float* emb    = (const float*)d_in[1];
  const float* Wf     = (const float*)d_in[2];
  const float* Uf     = (const float*)d_in[3];
  const float* bf     = (const float*)d_in[4];
  const float* Wb     = (const float*)d_in[5];
  const float* Ub     = (const float*)d_in[6];
  const float* bb     = (const float*)d_in[7];
  float* ws = (float*)d_ws;
  float* xw = ws;
  float* hb = ws + XW_FLOATS;
  int*   ctr = (int*)(hb + HB_FLOATS);
  float* out = (float*)d_out;
  float* state = out + (size_t)BB * TT * 1024;

  hipMemsetAsync(ctr, 0, 16 * 32 * sizeof(int), stream);
  hipLaunchKernelGGL(k_input_gemm, dim3(24, 512, 2), dim3(256), 0, stream,
                     tokens, emb, Wf, bf, Wb, bb, xw);
  hipLaunchKernelGGL(k_gru, dim3(256), dim3(256), 0, stream,
                     xw, Uf, Ub, bf, bb, hb, ctr, out, state);
}